// Round 1
// baseline (354.903 us; speedup 1.0000x reference)
//
#include <hip/hip_runtime.h>
#include <hip/hip_bf16.h>

// Sparsemax over rows of shape [N_ROWS, 64], fp32.
// One wave (64 lanes) per row; one element per lane.
//
// Reference semantics (note the DOUBLE -1):
//   s      = sort(x, descending)
//   cum    = cumsum(s) - 1
//   valid  = (s - cum/k) > 0,  k = 1..64
//   rho    = sum(valid)
//   tau    = (cum[rho-1] - 1) / rho
//   out    = max(0, x - tau)

__global__ __launch_bounds__(256) void sparsemax_kernel(
    const float* __restrict__ x, float* __restrict__ out, int n_rows) {
    const int lane = threadIdx.x & 63;
    const int wave_in_block = threadIdx.x >> 6;
    const int waves_per_block = blockDim.x >> 6;
    const long long wave_id = (long long)blockIdx.x * waves_per_block + wave_in_block;
    const long long n_waves = (long long)gridDim.x * waves_per_block;

    for (long long row = wave_id; row < n_rows; row += n_waves) {
        const long long base = row * 64 + lane;
        const float xv = x[base];

        // ---- bitonic sort, descending across 64 lanes ----
        float v = xv;
#pragma unroll
        for (int k = 2; k <= 64; k <<= 1) {
#pragma unroll
            for (int j = k >> 1; j >= 1; j >>= 1) {
                float o = __shfl_xor(v, j, 64);
                // lower lane of each pair takes max in "descending" blocks
                bool takeMax = ((lane & j) == 0) == ((lane & k) == 0);
                v = takeMax ? fmaxf(v, o) : fminf(v, o);
            }
        }

        // ---- inclusive cumsum across lanes (sorted order) ----
        float c = v;
#pragma unroll
        for (int off = 1; off < 64; off <<= 1) {
            float n = __shfl_up(c, off, 64);
            if (lane >= off) c += n;
        }
        c -= 1.0f;  // cum = cumsum - 1

        // ---- support size rho ----
        const float kf = (float)(lane + 1);
        const bool valid = (v - c / kf) > 0.0f;   // exact reference arithmetic
        const unsigned long long m = __ballot(valid);
        const int rho = __popcll(m);

        // ---- tau and output ----
        const float c_at = __shfl(c, rho - 1, 64);
        const float tau = (c_at - 1.0f) / (float)rho;
        out[base] = fmaxf(0.0f, xv - tau);
    }
}

extern "C" void kernel_launch(void* const* d_in, const int* in_sizes, int n_in,
                              void* d_out, int out_size, void* d_ws, size_t ws_size,
                              hipStream_t stream) {
    const float* x = (const float*)d_in[0];
    float* out = (float*)d_out;
    const int n_rows = in_sizes[0] / 64;

    const int block = 256;             // 4 waves/block
    const int grid = 4096;             // 16384 waves, grid-stride over rows
    sparsemax_kernel<<<grid, block, 0, stream>>>(x, out, n_rows);
}

// Round 2
// 187.528 us; speedup vs baseline: 1.8925x; 1.8925x over previous
//
#include <hip/hip_runtime.h>
#include <hip/hip_bf16.h>

// Sparsemax over rows of [N_ROWS, 64] fp32 — ONE ROW PER THREAD.
// Each lane holds its entire row in registers (64 VGPRs) plus a copy of the
// original values. The bitonic sort is a fully-unrolled static network of
// register min/max ops — no cross-lane shuffles, no LDS.
//
// Reference semantics (double -1):
//   s     = sort(x, descending)
//   cum_k = cumsum(s)_k - 1
//   valid = (s_k - cum_k/k) > 0          [sign computed via fmaf(k,s,-cum)]
//   rho   = #valid ; tau = (cum_rho - 1)/rho
//   out   = max(0, x - tau)

__global__ __launch_bounds__(256) void sparsemax_rowthread(
    const float* __restrict__ x, float* __restrict__ out, int n_rows) {
    const int row = blockIdx.x * 256 + threadIdx.x;
    if (row >= n_rows) return;

    const float4* __restrict__ xr = reinterpret_cast<const float4*>(x) + (size_t)row * 16;
    float4* __restrict__ orow = reinterpret_cast<float4*>(out) + (size_t)row * 16;

    float xv[64];   // original values (for the output pass)
    float v[64];    // sorted in place

#pragma unroll
    for (int j = 0; j < 16; ++j) {
        float4 t = xr[j];
        xv[4 * j + 0] = t.x;
        xv[4 * j + 1] = t.y;
        xv[4 * j + 2] = t.z;
        xv[4 * j + 3] = t.w;
    }
#pragma unroll
    for (int i = 0; i < 64; ++i) v[i] = xv[i];

    // ---- bitonic sort, descending, fully static network (672 CEs) ----
#pragma unroll
    for (int k = 2; k <= 64; k <<= 1) {
#pragma unroll
        for (int j = k >> 1; j >= 1; j >>= 1) {
#pragma unroll
            for (int i = 0; i < 64; ++i) {
                const int l = i ^ j;
                if (l > i) {
                    const float a = v[i], b = v[l];
                    const float mx = fmaxf(a, b), mn = fminf(a, b);
                    const bool up = ((i & k) == 0);  // compile-time after unroll
                    v[i] = up ? mx : mn;
                    v[l] = up ? mn : mx;
                }
            }
        }
    }

    // ---- rho / tau (serial per-thread scan over sorted values) ----
    float craw = 0.0f;   // raw cumsum
    float tc = 0.0f;     // cum at last valid k  (== cum[rho-1], prefix property)
    float rhof = 0.0f;
#pragma unroll
    for (int k = 1; k <= 64; ++k) {
        const float s = v[k - 1];
        craw += s;
        const float cum = craw - 1.0f;                      // cumsum - 1, ref order
        const bool valid = fmaf((float)k, s, -cum) > 0.0f;  // exact sign of s - cum/k
        tc = valid ? cum : tc;
        rhof = valid ? rhof + 1.0f : rhof;
    }
    const float tau = (tc - 1.0f) / rhof;

    // ---- output: max(0, x - tau) ----
#pragma unroll
    for (int j = 0; j < 16; ++j) {
        float4 t;
        t.x = fmaxf(0.0f, xv[4 * j + 0] - tau);
        t.y = fmaxf(0.0f, xv[4 * j + 1] - tau);
        t.z = fmaxf(0.0f, xv[4 * j + 2] - tau);
        t.w = fmaxf(0.0f, xv[4 * j + 3] - tau);
        orow[j] = t;
    }
}

extern "C" void kernel_launch(void* const* d_in, const int* in_sizes, int n_in,
                              void* d_out, int out_size, void* d_ws, size_t ws_size,
                              hipStream_t stream) {
    const float* x = (const float*)d_in[0];
    float* out = (float*)d_out;
    const int n_rows = in_sizes[0] / 64;

    const int block = 256;
    const int grid = (n_rows + block - 1) / block;  // 4096 for 1M rows
    sparsemax_rowthread<<<grid, block, 0, stream>>>(x, out, n_rows);
}

// Round 3
// 186.964 us; speedup vs baseline: 1.8982x; 1.0030x over previous
//
#include <hip/hip_runtime.h>
#include <hip/hip_bf16.h>

// Sparsemax over rows of [N_ROWS, 64] fp32 — ONE ROW PER THREAD.
// Each lane holds its entire row in registers (64 VGPRs for the sort array +
// 64 for the original values). __launch_bounds__(256, 1) releases the VGPR
// budget (up to 512/wave) so the compiler does NOT spill — round 2 showed
// VGPR_Count=68 + ~150 MB of scratch traffic when the allocator targeted
// high occupancy.
//
// Reference semantics (double -1):
//   s     = sort(x, descending)
//   cum_k = cumsum(s)_k - 1
//   valid = (s_k - cum_k/k) > 0          [sign computed via fmaf(k,s,-cum)]
//   rho   = #valid ; tau = (cum[rho-1] - 1)/rho
//   out   = max(0, x - tau)

__global__ __launch_bounds__(256, 1) void sparsemax_rowthread(
    const float* __restrict__ x, float* __restrict__ out, int n_rows) {
    const int row = blockIdx.x * 256 + threadIdx.x;
    if (row >= n_rows) return;

    const float4* __restrict__ xr = reinterpret_cast<const float4*>(x) + (size_t)row * 16;
    float4* __restrict__ orow = reinterpret_cast<float4*>(out) + (size_t)row * 16;

    float xv[64];   // original values (for the output pass)
    float v[64];    // sorted in place

#pragma unroll
    for (int j = 0; j < 16; ++j) {
        float4 t = xr[j];
        xv[4 * j + 0] = t.x;
        xv[4 * j + 1] = t.y;
        xv[4 * j + 2] = t.z;
        xv[4 * j + 3] = t.w;
    }
#pragma unroll
    for (int i = 0; i < 64; ++i) v[i] = xv[i];

    // ---- bitonic sort, descending, fully static network (672 CEs) ----
#pragma unroll
    for (int k = 2; k <= 64; k <<= 1) {
#pragma unroll
        for (int j = k >> 1; j >= 1; j >>= 1) {
#pragma unroll
            for (int i = 0; i < 64; ++i) {
                const int l = i ^ j;
                if (l > i) {
                    const float a = v[i], b = v[l];
                    const float mx = fmaxf(a, b), mn = fminf(a, b);
                    const bool up = ((i & k) == 0);  // compile-time after unroll
                    v[i] = up ? mx : mn;
                    v[l] = up ? mn : mx;
                }
            }
        }
    }

    // ---- rho / tau (serial per-thread scan over sorted values) ----
    float craw = 0.0f;   // raw cumsum
    float tc = 0.0f;     // cum at last valid k  (== cum[rho-1], prefix property)
    float rhof = 0.0f;
#pragma unroll
    for (int k = 1; k <= 64; ++k) {
        const float s = v[k - 1];
        craw += s;
        const float cum = craw - 1.0f;                      // cumsum - 1, ref order
        const bool valid = fmaf((float)k, s, -cum) > 0.0f;  // exact sign of s - cum/k
        tc = valid ? cum : tc;
        rhof = valid ? rhof + 1.0f : rhof;
    }
    const float tau = (tc - 1.0f) / rhof;

    // ---- output: max(0, x - tau) ----
#pragma unroll
    for (int j = 0; j < 16; ++j) {
        float4 t;
        t.x = fmaxf(0.0f, xv[4 * j + 0] - tau);
        t.y = fmaxf(0.0f, xv[4 * j + 1] - tau);
        t.z = fmaxf(0.0f, xv[4 * j + 2] - tau);
        t.w = fmaxf(0.0f, xv[4 * j + 3] - tau);
        orow[j] = t;
    }
}

extern "C" void kernel_launch(void* const* d_in, const int* in_sizes, int n_in,
                              void* d_out, int out_size, void* d_ws, size_t ws_size,
                              hipStream_t stream) {
    const float* x = (const float*)d_in[0];
    float* out = (float*)d_out;
    const int n_rows = in_sizes[0] / 64;

    const int block = 256;
    const int grid = (n_rows + block - 1) / block;  // 4096 for 1M rows
    sparsemax_rowthread<<<grid, block, 0, stream>>>(x, out, n_rows);
}

// Round 4
// 161.264 us; speedup vs baseline: 2.2008x; 1.1594x over previous
//
#include <hip/hip_runtime.h>
#include <hip/hip_bf16.h>
#include <math.h>

// Sparsemax over rows of [N_ROWS, 64] fp32 — one row per thread, NO ARRAYS.
//
// Rounds 2-3 showed float v[64] arrays are never promoted out of scratch
// (VGPR_Count=68 + ~120MB spill traffic regardless of launch_bounds). Fix:
// hold the row in 16 named float4 registers (macro-expanded — no alloca),
// and replace the full sort with Michelot's fixed-point iteration for the
// simplex-projection threshold:
//
//   tau* = (sum_{x>tau*} x - 1) / |{x>tau*}|     (z=1 support, == reference rho)
//   init tau0 = max(x) - 1  (lower bound; iterates increase monotonically)
//   converged when support count stops changing (sets are nested)
//
// Reference's double -1 shifts only the output threshold:
//   tau_out = (sum_S - 2)/rho = tau* - 1/rho
//   out = max(0, x - tau_out)

#define FOR16(OP) OP(0) OP(1) OP(2) OP(3) OP(4) OP(5) OP(6) OP(7) \
                  OP(8) OP(9) OP(10) OP(11) OP(12) OP(13) OP(14) OP(15)

__global__ __launch_bounds__(256, 4) void sparsemax_michelot(
    const float* __restrict__ x, float* __restrict__ out, int n_rows) {
    const int row = blockIdx.x * 256 + threadIdx.x;
    if (row >= n_rows) return;

    const float4* __restrict__ xr = reinterpret_cast<const float4*>(x) + (size_t)row * 16;
    float4* __restrict__ orow = reinterpret_cast<float4*>(out) + (size_t)row * 16;

    // ---- load row into 16 named float4s (64 VGPRs, no alloca) ----
#define LD(i) float4 a##i = xr[i];
    FOR16(LD)
#undef LD

    // ---- row max ----
    float m = -INFINITY;
#define MX(i) m = fmaxf(m, fmaxf(fmaxf(a##i.x, a##i.y), fmaxf(a##i.z, a##i.w)));
    FOR16(MX)
#undef MX

    float tau = m - 1.0f;   // lower bound on tau*
    int cnt = 0;            // impossible count -> at least one more iteration
    float cfin = 1.0f;

    for (;;) {
        float s = 0.0f;
        int c = 0;
#define ACC(i)                                          \
        s += (a##i.x > tau) ? a##i.x : 0.0f;            \
        c += (a##i.x > tau) ? 1 : 0;                    \
        s += (a##i.y > tau) ? a##i.y : 0.0f;            \
        c += (a##i.y > tau) ? 1 : 0;                    \
        s += (a##i.z > tau) ? a##i.z : 0.0f;            \
        c += (a##i.z > tau) ? 1 : 0;                    \
        s += (a##i.w > tau) ? a##i.w : 0.0f;            \
        c += (a##i.w > tau) ? 1 : 0;
        FOR16(ACC)
#undef ACC
        const float cf = (float)c;
        const float tau_new = (s - 1.0f) / cf;
        const bool done = (c == cnt);   // nested sets: same count == same set
        cnt = c;
        cfin = cf;
        tau = tau_new;                  // idempotent once converged
        if (__all(done)) break;
    }

    const float tau_out = tau - 1.0f / cfin;   // (sum_S - 2)/rho

    // ---- output: max(0, x - tau_out) ----
#define ST(i) {                                         \
        float4 t;                                       \
        t.x = fmaxf(0.0f, a##i.x - tau_out);            \
        t.y = fmaxf(0.0f, a##i.y - tau_out);            \
        t.z = fmaxf(0.0f, a##i.z - tau_out);            \
        t.w = fmaxf(0.0f, a##i.w - tau_out);            \
        orow[i] = t; }
    FOR16(ST)
#undef ST
}

extern "C" void kernel_launch(void* const* d_in, const int* in_sizes, int n_in,
                              void* d_out, int out_size, void* d_ws, size_t ws_size,
                              hipStream_t stream) {
    const float* x = (const float*)d_in[0];
    float* out = (float*)d_out;
    const int n_rows = in_sizes[0] / 64;

    const int block = 256;
    const int grid = (n_rows + block - 1) / block;  // 4096 for 1M rows
    sparsemax_michelot<<<grid, block, 0, stream>>>(x, out, n_rows);
}